// Round 10
// baseline (235.384 us; speedup 1.0000x reference)
//
#include <hip/hip_runtime.h>

#define DIN 256
#define DH  128
#define DOUT 64
#define BSH  7          // bucket = 128 nodes
#define BNODES 128
#define MAXBUK 400      // >= ceil(N/128); N=50000 -> 391
#define NBLK 512        // histogram/scatter grid

typedef unsigned int  u32;
typedef unsigned short u16;
typedef __attribute__((ext_vector_type(8))) short bf16x8;
typedef __attribute__((ext_vector_type(4))) float f32x4;

__device__ inline u16 f2bf(float f) {            // fp32 -> bf16 round-nearest-even
  u32 u = __float_as_uint(f);
  u32 r = u + 0x7FFF + ((u >> 16) & 1);
  return (u16)(r >> 16);
}
__device__ inline float bf2f_lo(u32 packed) { return __uint_as_float(packed << 16); }
__device__ inline float bf2f_hi(u32 packed) { return __uint_as_float(packed & 0xFFFF0000u); }

// ---------- CSR construction ----------

// hist + w_prep merged (512x256 threads cover the 40960 weight elements).
// Also zeroes the col_scan ticket (kernel-boundary ordering makes it visible).
__global__ __launch_bounds__(256) void hist_kernel(const int* __restrict__ dst,
    int* __restrict__ counts, const float* __restrict__ W1,
    const float* __restrict__ W2, u16* __restrict__ w1t, u16* __restrict__ w2t,
    int* __restrict__ ticket, int E, int nbuk) {
  __shared__ int h[MAXBUK];
  int tid = threadIdx.x, b = blockIdx.x;
  if (b == 0 && tid == 0) *ticket = 0;
  {   // w_prep ride-along
    int t = b * 256 + tid;
    if (t < DH * DIN) {
      int n = t >> 8, k = t & 255;
      w1t[t] = f2bf(W1[k * DH + n]);            // w1t[n*256+k]
    } else if (t < DH * DIN + DOUT * DH) {
      int t2 = t - DH * DIN;                    // 0..8191
      int j = t2 >> 7, k = t2 & 127;
      w2t[t2] = f2bf(W2[k * DOUT + j]);         // w2t[j*128+k]  (W2^T, bf16)
    }
  }
  for (int i = tid; i < nbuk; i += 256) h[i] = 0;
  __syncthreads();
  int ech = (E + NBLK - 1) / NBLK;
  int e0 = b * ech, e1 = min(E, e0 + ech);
  for (int e = e0 + tid; e < e1; e += 256)
    atomicAdd(&h[dst[e] >> BSH], 1);
  __syncthreads();
  for (int i = tid; i < nbuk; i += 256) counts[(size_t)i * NBLK + b] = h[i];
}

// col_scan + bucket-total scan fused via last-block pattern (no grid.sync).
// Each block scans its bucket's 512 block-counts; last-arriving block does the
// 391-entry exclusive scan of bucket totals -> bb, bb[nbuk] = E.
__global__ __launch_bounds__(256) void col_scan_fused(int* __restrict__ counts,
    int* __restrict__ bb, int* __restrict__ ticket, int nbuk) {
  __shared__ int sm[256];
  __shared__ int carry;
  __shared__ int islast;
  int buk = blockIdx.x, t = threadIdx.x;
  if (t == 0) carry = 0;
  __syncthreads();
  int* row = counts + (size_t)buk * NBLK;
  for (int base = 0; base < NBLK; base += 256) {
    int v = row[base + t];
    sm[t] = v;
    __syncthreads();
    for (int d = 1; d < 256; d <<= 1) {
      int a = (t >= d) ? sm[t - d] : 0;
      __syncthreads();
      sm[t] += a;
      __syncthreads();
    }
    int excl = sm[t] - v + carry;
    row[base + t] = excl;
    __syncthreads();
    if (t == 255) carry = excl + v;
    __syncthreads();
  }
  if (t == 0) {
    bb[buk] = carry;                 // bucket total
    __threadfence();                 // release: total visible device-wide
    islast = (atomicAdd(ticket, 1) == nbuk - 1);
  }
  __syncthreads();
  if (islast) {                      // all other blocks have published totals
    __threadfence();                 // acquire side
    if (t == 0) carry = 0;
    __syncthreads();
    for (int base = 0; base < nbuk; base += 256) {
      int g = base + t;
      int v = (g < nbuk) ? bb[g] : 0;
      sm[t] = v;
      __syncthreads();
      for (int d = 1; d < 256; d <<= 1) {
        int add = (t >= d) ? sm[t - d] : 0;
        __syncthreads();
        sm[t] += add;
        __syncthreads();
      }
      int excl = sm[t] - v + carry;
      if (g < nbuk) bb[g] = excl;
      __syncthreads();
      if (t == 255) carry = excl + v;
      __syncthreads();
    }
    if (t == 0) bb[nbuk] = carry;
  }
}

__global__ __launch_bounds__(256) void scatter_kernel(const int* __restrict__ src,
    const int* __restrict__ dst, const int* __restrict__ counts,
    const int* __restrict__ bb, u32* __restrict__ ebuf, int E, int nbuk) {
  __shared__ int cur[MAXBUK];
  int tid = threadIdx.x, b = blockIdx.x;
  for (int i = tid; i < nbuk; i += 256)
    cur[i] = bb[i] + counts[(size_t)i * NBLK + b];
  __syncthreads();
  int ech = (E + NBLK - 1) / NBLK;
  int e0 = b * ech, e1 = min(E, e0 + ech);
  for (int e = e0 + tid; e < e1; e += 256) {
    int d = dst[e];
    int r = atomicAdd(&cur[d >> BSH], 1);
    ebuf[r] = (u32)src[e] | ((u32)(d & (BNODES - 1)) << 16);   // N < 65536
  }
}

// per-bucket: count + local exclusive scan -> rowptr/dinv, then fill csr.
__global__ __launch_bounds__(256) void bucket_finish(const u32* __restrict__ ebuf,
    const int* __restrict__ bb, int* __restrict__ rowptr, float* __restrict__ dinv,
    u16* __restrict__ csr, int N, int nbuk) {
  __shared__ int c[BNODES];
  __shared__ int ex[BNODES];
  int b = blockIdx.x, tid = threadIdx.x;
  if (tid < BNODES) c[tid] = 0;
  __syncthreads();
  int e0 = bb[b], e1 = bb[b + 1];
  for (int e = e0 + tid; e < e1; e += 256)
    atomicAdd(&c[ebuf[e] >> 16], 1);
  __syncthreads();
  if (tid < BNODES) ex[tid] = c[tid];
  __syncthreads();
  for (int d = 1; d < BNODES; d <<= 1) {
    int add = (tid >= d && tid < BNODES) ? ex[tid - d] : 0;
    __syncthreads();
    if (tid < BNODES) ex[tid] += add;
    __syncthreads();
  }
  if (tid < BNODES) {
    int cn = c[tid];
    int excl = ex[tid] - cn;                 // exclusive in-bucket offset
    int node = b * BNODES + tid;
    if (node < N) {
      rowptr[node] = e0 + excl;
      dinv[node] = rsqrtf((float)(cn + 1));  // +1 self-loop
    }
    c[tid] = e0 + excl;                      // cursor
  }
  if (b == 0 && tid == 0) rowptr[N] = bb[nbuk];
  __syncthreads();
  for (int e = e0 + tid; e < e1; e += 256) {
    u32 p = ebuf[e];
    int nl = p >> 16;
    int r = atomicAdd(&c[nl], 1);
    csr[r] = (u16)(p & 0xFFFFu);
  }
}

// ---------- GEMM1: bf16 MFMA, BM=64 BN=128 BK=64, epilogue dinv*bf16 ----------

__global__ __launch_bounds__(256) void gemm1_mfma(const float* __restrict__ x,
    const u16* __restrict__ w1t, const float* __restrict__ dinv,
    u16* __restrict__ h1, int M) {
  __shared__ u16 As[64][72];
  __shared__ u16 Bs[128][72];
  const int tid = threadIdx.x;
  const int lane = tid & 63, w = tid >> 6;
  const int row16 = lane & 15, quad = lane >> 4;
  const int rowBase = blockIdx.x * 64;
  f32x4 acc[8];
  #pragma unroll
  for (int nt = 0; nt < 8; ++nt) acc[nt] = (f32x4)(0.f);

  for (int kt = 0; kt < DIN; kt += 64) {
    {
      int r = tid >> 2, kq = tid & 3;
      int grow = rowBase + r;
      #pragma unroll
      for (int i = 0; i < 4; ++i) {
        float4 v = make_float4(0.f, 0.f, 0.f, 0.f);
        if (grow < M) v = *(const float4*)&x[(size_t)grow * DIN + kt + kq * 16 + i * 4];
        u32 lo = (u32)f2bf(v.x) | ((u32)f2bf(v.y) << 16);
        u32 hi = (u32)f2bf(v.z) | ((u32)f2bf(v.w) << 16);
        *(uint2*)&As[r][kq * 16 + i * 4] = make_uint2(lo, hi);
      }
    }
    {
      int n = tid >> 1, half = tid & 1;
      const uint4* s = (const uint4*)&w1t[n * DIN + kt + half * 32];
      uint4* d = (uint4*)&Bs[n][half * 32];
      d[0] = s[0]; d[1] = s[1]; d[2] = s[2]; d[3] = s[3];
    }
    __syncthreads();
    #pragma unroll
    for (int ks = 0; ks < 64; ks += 32) {
      bf16x8 a = *(bf16x8*)&As[w * 16 + row16][ks + quad * 8];
      #pragma unroll
      for (int nt = 0; nt < 8; ++nt) {
        bf16x8 b = *(bf16x8*)&Bs[nt * 16 + row16][ks + quad * 8];
        acc[nt] = __builtin_amdgcn_mfma_f32_16x16x32_bf16(a, b, acc[nt], 0, 0, 0);
      }
    }
    __syncthreads();
  }
  #pragma unroll
  for (int reg = 0; reg < 4; ++reg) {
    int row = rowBase + w * 16 + quad * 4 + reg;
    if (row < M) {
      float s = dinv[row];
      #pragma unroll
      for (int nt = 0; nt < 8; ++nt)
        h1[(size_t)row * DH + nt * 16 + row16] = f2bf(acc[nt][reg] * s);
    }
  }
}

// ---------- aggregate1 fused with layer-2 transform via MFMA (unchanged) ----------

__global__ __launch_bounds__(256) void aggregate1_fused(const u16* __restrict__ h,
    const int* __restrict__ rowptr, const u16* __restrict__ csr,
    const float* __restrict__ dinv, const float* __restrict__ bias,
    const u16* __restrict__ w2t, u16* __restrict__ h2, int n) {
  __shared__ __align__(16) u16 w2s[64 * 136];     // W2^T [64 cols][128 k], padded rows
  __shared__ __align__(16) u16 rowbuf[16 * 136];  // 16 M-rows (4 real), padded
  const int tid = threadIdx.x;
  const int lane = tid & 63;
  const int wv = tid >> 6;
  const int row16 = lane & 15, quad = lane >> 4;

  {   // stage W2^T: 64 rows x 16 uint4, row-padded
    #pragma unroll
    for (int i = 0; i < 4; ++i) {
      int flat = i * 256 + tid;                  // 0..1023
      int r = flat >> 4, q = flat & 15;
      *(uint4*)&w2s[r * 136 + q * 8] = *(const uint4*)&w2t[r * 128 + q * 8];
    }
  }
  if (wv < 3) {     // zero pad rows 4..15 of rowbuf (waves 0-2, one store/lane)
    int r = 4 + wv * 4 + quad;
    *(uint4*)&rowbuf[r * 136 + row16 * 8] = make_uint4(0, 0, 0, 0);
  }

  const int sub = quad;               // edge slot within quartet (0..3)
  const int l16 = row16;              // 16B chunk within 256B row
  const int nodeBase = blockIdx.x * 4;
  int node = nodeBase + wv;
  const bool active = node < n;
  node = __builtin_amdgcn_readfirstlane(active ? node : (n - 1));
  const float di = dinv[node];
  const size_t coff = (size_t)l16 * 8;

  float a[8];
  {   // self-loop row (only sub==0 keeps it)
    uint4 v = *(const uint4*)&h[(size_t)node * DH + coff];
    float ms = (sub == 0) ? 1.f : 0.f;
    a[0] = ms * bf2f_lo(v.x); a[1] = ms * bf2f_hi(v.x);
    a[2] = ms * bf2f_lo(v.y); a[3] = ms * bf2f_hi(v.y);
    a[4] = ms * bf2f_lo(v.z); a[5] = ms * bf2f_hi(v.z);
    a[6] = ms * bf2f_lo(v.w); a[7] = ms * bf2f_hi(v.w);
  }

  int p = rowptr[node];
  const int pe = active ? rowptr[node + 1] : p;   // inactive wave: empty range
  while (p < pe) {
    int g = p + lane;
    int si = (g < pe) ? (int)csr[g] : 0;     // 64 indices, one instruction
    int rem = pe - p; if (rem > 64) rem = 64;
    int t = 0;
    for (; t + 16 <= rem; t += 16) {         // 4 x 1KB gathers in flight
      #pragma unroll
      for (int q = 0; q < 4; ++q) {
        int idx = __shfl(si, t + q * 4 + sub, 64);
        uint4 v = *(const uint4*)&h[(size_t)idx * DH + coff];
        a[0] += bf2f_lo(v.x); a[1] += bf2f_hi(v.x);
        a[2] += bf2f_lo(v.y); a[3] += bf2f_hi(v.y);
        a[4] += bf2f_lo(v.z); a[5] += bf2f_hi(v.z);
        a[6] += bf2f_lo(v.w); a[7] += bf2f_hi(v.w);
      }
    }
    for (; t < rem; t += 4) {                // masked remainder (1-15 edges)
      int e = t + sub;
      int idx = __shfl(si, e & 63, 64);
      uint4 v = *(const uint4*)&h[(size_t)idx * DH + coff];
      float m = (e < rem) ? 1.f : 0.f;
      a[0] = fmaf(m, bf2f_lo(v.x), a[0]); a[1] = fmaf(m, bf2f_hi(v.x), a[1]);
      a[2] = fmaf(m, bf2f_lo(v.y), a[2]); a[3] = fmaf(m, bf2f_hi(v.y), a[3]);
      a[4] = fmaf(m, bf2f_lo(v.z), a[4]); a[5] = fmaf(m, bf2f_hi(v.z), a[5]);
      a[6] = fmaf(m, bf2f_lo(v.w), a[6]); a[7] = fmaf(m, bf2f_hi(v.w), a[7]);
    }
    p += 64;
  }

  #pragma unroll
  for (int i = 0; i < 8; ++i) {              // butterfly: every lane gets full sum
    a[i] += __shfl_xor(a[i], 16, 64);
    a[i] += __shfl_xor(a[i], 32, 64);
  }

  // g1 = relu(a*di + b1) -> bf16 -> rowbuf row wv (sub==0 lanes, one b128 store)
  if (sub == 0) {
    const int c0 = l16 * 8;
    float4 b0 = *(const float4*)&bias[c0];
    float4 b1v = *(const float4*)&bias[c0 + 4];
    float f0 = fmaxf(fmaf(a[0], di, b0.x), 0.f);
    float f1 = fmaxf(fmaf(a[1], di, b0.y), 0.f);
    float f2 = fmaxf(fmaf(a[2], di, b0.z), 0.f);
    float f3 = fmaxf(fmaf(a[3], di, b0.w), 0.f);
    float f4 = fmaxf(fmaf(a[4], di, b1v.x), 0.f);
    float f5 = fmaxf(fmaf(a[5], di, b1v.y), 0.f);
    float f6 = fmaxf(fmaf(a[6], di, b1v.z), 0.f);
    float f7 = fmaxf(fmaf(a[7], di, b1v.w), 0.f);
    uint4 pk;
    pk.x = (u32)f2bf(f0) | ((u32)f2bf(f1) << 16);
    pk.y = (u32)f2bf(f2) | ((u32)f2bf(f3) << 16);
    pk.z = (u32)f2bf(f4) | ((u32)f2bf(f5) << 16);
    pk.w = (u32)f2bf(f6) | ((u32)f2bf(f7) << 16);
    *(uint4*)&rowbuf[wv * 136 + l16 * 8] = pk;
  }
  __syncthreads();

  // block matmul: [16 x 128](rows 0-3 real) @ W2^T -> each wave owns 16 cols
  f32x4 acc = (f32x4)(0.f);
  #pragma unroll
  for (int kt = 0; kt < 4; ++kt) {
    bf16x8 af = *(bf16x8*)&rowbuf[row16 * 136 + kt * 32 + quad * 8];
    bf16x8 bf = *(bf16x8*)&w2s[(wv * 16 + row16) * 136 + kt * 32 + quad * 8];
    acc = __builtin_amdgcn_mfma_f32_16x16x32_bf16(af, bf, acc, 0, 0, 0);
  }
  // C layout: col = lane&15, row = (lane>>4)*4 + reg; rows 0-3 live in quad==0
  if (quad == 0) {
    #pragma unroll
    for (int reg = 0; reg < 4; ++reg) {
      int nr = nodeBase + reg;
      if (nr < n)
        h2[(size_t)nr * DOUT + wv * 16 + row16] = f2bf(acc[reg] * dinv[nr]);
    }
  }
}

// ---------- aggregate2: 8 edge-groups x 8 lanes, u16 csr (unchanged) ----------

__global__ __launch_bounds__(256) void aggregate2(const u16* __restrict__ h,
    const int* __restrict__ rowptr, const u16* __restrict__ csr,
    const float* __restrict__ dinv, const float* __restrict__ bias,
    float* __restrict__ out, int n) {
  const int lane = threadIdx.x & 63;
  const int sub = lane >> 3;          // edge slot within octet (0..7)
  const int l8 = lane & 7;            // 16B chunk within 128B row
  int node = blockIdx.x * 4 + (threadIdx.x >> 6);
  if (node >= n) return;
  node = __builtin_amdgcn_readfirstlane(node);
  const float di = dinv[node];
  const size_t coff = (size_t)l8 * 8;

  float a[8];
  {
    uint4 v = *(const uint4*)&h[(size_t)node * DOUT + coff];
    float ms = (sub == 0) ? 1.f : 0.f;
    a[0] = ms * bf2f_lo(v.x); a[1] = ms * bf2f_hi(v.x);
    a[2] = ms * bf2f_lo(v.y); a[3] = ms * bf2f_hi(v.y);
    a[4] = ms * bf2f_lo(v.z); a[5] = ms * bf2f_hi(v.z);
    a[6] = ms * bf2f_lo(v.w); a[7] = ms * bf2f_hi(v.w);
  }

  int p = rowptr[node];
  const int pe = rowptr[node + 1];
  while (p < pe) {
    int g = p + lane;
    int si = (g < pe) ? (int)csr[g] : 0;
    int rem = pe - p; if (rem > 64) rem = 64;
    int t = 0;
    for (; t + 32 <= rem; t += 32) {         // 4 x 1KB gathers in flight
      #pragma unroll
      for (int q = 0; q < 4; ++q) {
        int idx = __shfl(si, t + q * 8 + sub, 64);
        uint4 v = *(const uint4*)&h[(size_t)idx * DOUT + coff];
        a[0] += bf2f_lo(v.x); a[1] += bf2f_hi(v.x);
        a[2] += bf2f_lo(v.y); a[3] += bf2f_hi(v.y);
        a[4] += bf2f_lo(v.z); a[5] += bf2f_hi(v.z);
        a[6] += bf2f_lo(v.w); a[7] += bf2f_hi(v.w);
      }
    }
    for (; t < rem; t += 8) {                // masked remainder (1-31 edges)
      int e = t + sub;
      int idx = __shfl(si, e & 63, 64);
      uint4 v = *(const uint4*)&h[(size_t)idx * DOUT + coff];
      float m = (e < rem) ? 1.f : 0.f;
      a[0] = fmaf(m, bf2f_lo(v.x), a[0]); a[1] = fmaf(m, bf2f_hi(v.x), a[1]);
      a[2] = fmaf(m, bf2f_lo(v.y), a[2]); a[3] = fmaf(m, bf2f_hi(v.y), a[3]);
      a[4] = fmaf(m, bf2f_lo(v.z), a[4]); a[5] = fmaf(m, bf2f_hi(v.z), a[5]);
      a[6] = fmaf(m, bf2f_lo(v.w), a[6]); a[7] = fmaf(m, bf2f_hi(v.w), a[7]);
    }
    p += 64;
  }

  #pragma unroll
  for (int i = 0; i < 8; ++i) {              // reduce across the 8 edge-groups
    a[i] += __shfl_xor(a[i], 8, 64);
    a[i] += __shfl_xor(a[i], 16, 64);
    a[i] += __shfl_xor(a[i], 32, 64);
  }

  if (sub == 0) {                            // lanes 0..7 hold the full row
    const int c0 = l8 * 8;
    float4 b0 = *(const float4*)&bias[c0];
    float4 b1 = *(const float4*)&bias[c0 + 4];
    float4 r0, r1;
    r0.x = fmaf(a[0], di, b0.x);
    r0.y = fmaf(a[1], di, b0.y);
    r0.z = fmaf(a[2], di, b0.z);
    r0.w = fmaf(a[3], di, b0.w);
    r1.x = fmaf(a[4], di, b1.x);
    r1.y = fmaf(a[5], di, b1.y);
    r1.z = fmaf(a[6], di, b1.z);
    r1.w = fmaf(a[7], di, b1.w);
    *(float4*)&out[(size_t)node * DOUT + c0] = r0;
    *(float4*)&out[(size_t)node * DOUT + c0 + 4] = r1;
  }
}

// ---------- launch ----------

extern "C" void kernel_launch(void* const* d_in, const int* in_sizes, int n_in,
                              void* d_out, int out_size, void* d_ws, size_t ws_size,
                              hipStream_t stream) {
  const float* x  = (const float*)d_in[0];
  const int*   ei = (const int*)d_in[1];
  const float* W1 = (const float*)d_in[2];
  const float* b1 = (const float*)d_in[3];
  const float* W2 = (const float*)d_in[4];
  const float* b2 = (const float*)d_in[5];
  float* out = (float*)d_out;

  const int N = in_sizes[0] / DIN;   // 50000
  const int E = in_sizes[1] / 2;     // 1600000
  const int* src = ei;
  const int* dst = ei + E;
  const int nbuk = (N + BNODES - 1) / BNODES;   // 391 (<= MAXBUK)

  char* ws = (char*)d_ws;
  size_t o = 0;
  auto alloc = [&](size_t bytes) { size_t r = o; o += (bytes + 511) & ~(size_t)511; return r; };
  size_t bb_o      = alloc((size_t)(nbuk + 1) * 4);
  size_t ticket_o  = alloc(4);
  size_t counts_o  = alloc((size_t)nbuk * NBLK * 4);
  size_t rowptr_o  = alloc((size_t)(N + 1) * 4);
  size_t dinv_o    = alloc((size_t)N * 4);
  size_t w1t_o     = alloc((size_t)DH * DIN * 2);
  size_t w2t_o     = alloc((size_t)DOUT * DH * 2);
  size_t csr_o     = alloc((size_t)E * 2);        // u16 indices
  size_t h1_o      = alloc((size_t)N * DH * 2);   // bf16
  size_t big_o     = alloc((size_t)E * 4);        // ebuf, later h2
  size_t h2_o      = big_o;   // ebuf dead after bucket_finish -> h2 (bf16, 6.4MB)

  int*   bb      = (int*)(ws + bb_o);
  int*   ticket  = (int*)(ws + ticket_o);
  int*   counts  = (int*)(ws + counts_o);
  int*   rowptr  = (int*)(ws + rowptr_o);
  float* dinv    = (float*)(ws + dinv_o);
  u16*   w1t     = (u16*)(ws + w1t_o);
  u16*   w2t     = (u16*)(ws + w2t_o);
  u16*   csr     = (u16*)(ws + csr_o);
  u16*   h1      = (u16*)(ws + h1_o);
  u32*   ebuf    = (u32*)(ws + big_o);
  u16*   h2      = (u16*)(ws + h2_o);

  hist_kernel<<<NBLK, 256, 0, stream>>>(dst, counts, W1, W2, w1t, w2t, ticket, E, nbuk);
  col_scan_fused<<<nbuk, 256, 0, stream>>>(counts, bb, ticket, nbuk);
  scatter_kernel<<<NBLK, 256, 0, stream>>>(src, dst, counts, bb, ebuf, E, nbuk);
  bucket_finish<<<nbuk, 256, 0, stream>>>(ebuf, bb, rowptr, dinv, csr, N, nbuk);

  gemm1_mfma<<<(N + 63) / 64, 256, 0, stream>>>(x, w1t, dinv, h1, N);
  aggregate1_fused<<<(N + 3) / 4, 256, 0, stream>>>(h1, rowptr, csr, dinv, b1, w2t, h2, N);
  aggregate2<<<(N + 3) / 4, 256, 0, stream>>>(h2, rowptr, csr, dinv, b2, out, N);
}

// Round 11
// 229.584 us; speedup vs baseline: 1.0253x; 1.0253x over previous
//
#include <hip/hip_runtime.h>

#define DIN 256
#define DH  128
#define DOUT 64
#define BSH  7          // bucket = 128 nodes
#define BNODES 128
#define MAXBUK 400      // >= ceil(N/128); N=50000 -> 391
#define NBLK 512        // histogram/scatter grid

typedef unsigned int  u32;
typedef unsigned short u16;
typedef __attribute__((ext_vector_type(8))) short bf16x8;
typedef __attribute__((ext_vector_type(4))) float f32x4;

__device__ inline u16 f2bf(float f) {            // fp32 -> bf16 round-nearest-even
  u32 u = __float_as_uint(f);
  u32 r = u + 0x7FFF + ((u >> 16) & 1);
  return (u16)(r >> 16);
}
__device__ inline float bf2f_lo(u32 packed) { return __uint_as_float(packed << 16); }
__device__ inline float bf2f_hi(u32 packed) { return __uint_as_float(packed & 0xFFFF0000u); }

// ---------- CSR construction ----------

__global__ __launch_bounds__(256) void hist_kernel(const int* __restrict__ dst,
    int* __restrict__ counts, int E, int nbuk) {
  __shared__ int h[MAXBUK];
  int tid = threadIdx.x, b = blockIdx.x;
  for (int i = tid; i < nbuk; i += 256) h[i] = 0;
  __syncthreads();
  int ech = (E + NBLK - 1) / NBLK;
  int e0 = b * ech, e1 = min(E, e0 + ech);
  for (int e = e0 + tid; e < e1; e += 256)
    atomicAdd(&h[dst[e] >> BSH], 1);
  __syncthreads();
  for (int i = tid; i < nbuk; i += 256) counts[(size_t)i * NBLK + b] = h[i];
}

__global__ __launch_bounds__(256) void col_scan(int* __restrict__ counts,
    int* __restrict__ colsum, int nbuk) {
  __shared__ int sm[256];
  __shared__ int carry;
  int buk = blockIdx.x, t = threadIdx.x;
  if (t == 0) carry = 0;
  __syncthreads();
  int* row = counts + (size_t)buk * NBLK;
  for (int base = 0; base < NBLK; base += 256) {
    int v = row[base + t];
    sm[t] = v;
    __syncthreads();
    for (int d = 1; d < 256; d <<= 1) {
      int a = (t >= d) ? sm[t - d] : 0;
      __syncthreads();
      sm[t] += a;
      __syncthreads();
    }
    int excl = sm[t] - v + carry;
    row[base + t] = excl;
    __syncthreads();
    if (t == 255) carry = excl + v;
    __syncthreads();
  }
  if (t == 0) colsum[buk] = carry;
}

__global__ __launch_bounds__(256) void scan_block(int* partial, int* total_out, int nb, int n) {
  __shared__ int sm[256];
  __shared__ int carry;
  int t = threadIdx.x;
  if (t == 0) carry = 0;
  __syncthreads();
  for (int base = 0; base < nb; base += 256) {
    int g = base + t;
    int v = (g < nb) ? partial[g] : 0;
    sm[t] = v;
    __syncthreads();
    for (int d = 1; d < 256; d <<= 1) {
      int add = (t >= d) ? sm[t - d] : 0;
      __syncthreads();
      sm[t] += add;
      __syncthreads();
    }
    int excl = sm[t] - v + carry;
    if (g < nb) partial[g] = excl;
    __syncthreads();
    if (t == 255) carry = excl + v;
    __syncthreads();
  }
  if (t == 0) total_out[n] = carry;
}

__global__ __launch_bounds__(256) void scatter_kernel(const int* __restrict__ src,
    const int* __restrict__ dst, const int* __restrict__ counts,
    const int* __restrict__ bb, u32* __restrict__ ebuf, int E, int nbuk) {
  __shared__ int cur[MAXBUK];
  int tid = threadIdx.x, b = blockIdx.x;
  for (int i = tid; i < nbuk; i += 256)
    cur[i] = bb[i] + counts[(size_t)i * NBLK + b];
  __syncthreads();
  int ech = (E + NBLK - 1) / NBLK;
  int e0 = b * ech, e1 = min(E, e0 + ech);
  for (int e = e0 + tid; e < e1; e += 256) {
    int d = dst[e];
    int r = atomicAdd(&cur[d >> BSH], 1);
    ebuf[r] = (u32)src[e] | ((u32)(d & (BNODES - 1)) << 16);   // N < 65536
  }
}

// per-bucket: count + local exclusive scan -> rowptr/dinv, then fill csr.
// Replaces bucket_node_count + scan_block#2 + scan_chunks + bucket_fill.
__global__ __launch_bounds__(256) void bucket_finish(const u32* __restrict__ ebuf,
    const int* __restrict__ bb, int* __restrict__ rowptr, float* __restrict__ dinv,
    u16* __restrict__ csr, int N, int nbuk) {
  __shared__ int c[BNODES];
  __shared__ int ex[BNODES];
  int b = blockIdx.x, tid = threadIdx.x;
  if (tid < BNODES) c[tid] = 0;
  __syncthreads();
  int e0 = bb[b], e1 = bb[b + 1];
  for (int e = e0 + tid; e < e1; e += 256)
    atomicAdd(&c[ebuf[e] >> 16], 1);
  __syncthreads();
  if (tid < BNODES) ex[tid] = c[tid];
  __syncthreads();
  for (int d = 1; d < BNODES; d <<= 1) {
    int add = (tid >= d && tid < BNODES) ? ex[tid - d] : 0;
    __syncthreads();
    if (tid < BNODES) ex[tid] += add;
    __syncthreads();
  }
  if (tid < BNODES) {
    int cn = c[tid];
    int excl = ex[tid] - cn;                 // exclusive in-bucket offset
    int node = b * BNODES + tid;
    if (node < N) {
      rowptr[node] = e0 + excl;
      dinv[node] = rsqrtf((float)(cn + 1));  // +1 self-loop
    }
    c[tid] = e0 + excl;                      // cursor
  }
  if (b == 0 && tid == 0) rowptr[N] = bb[nbuk];
  __syncthreads();
  for (int e = e0 + tid; e < e1; e += 256) {
    u32 p = ebuf[e];
    int nl = p >> 16;
    int r = atomicAdd(&c[nl], 1);
    csr[r] = (u16)(p & 0xFFFFu);
  }
}

// ---------- W1 -> bf16 transposed; W2 -> bf16 transposed [64][128] ----------

__global__ __launch_bounds__(256) void w_prep(const float* __restrict__ W1,
    const float* __restrict__ W2, u16* __restrict__ w1t, u16* __restrict__ w2t) {
  int t = blockIdx.x * 256 + threadIdx.x;     // 40960 threads
  if (t < DH * DIN) {
    int n = t >> 8, k = t & 255;
    w1t[t] = f2bf(W1[k * DH + n]);            // w1t[n*256+k]
  } else {
    int t2 = t - DH * DIN;                    // 0..8191
    int j = t2 >> 7, k = t2 & 127;
    w2t[t2] = f2bf(W2[k * DOUT + j]);         // w2t[j*128+k]  (W2^T, bf16)
  }
}

// ---------- GEMM1: bf16 MFMA, BM=64 BN=128 BK=64, epilogue dinv*bf16 ----------

__global__ __launch_bounds__(256) void gemm1_mfma(const float* __restrict__ x,
    const u16* __restrict__ w1t, const float* __restrict__ dinv,
    u16* __restrict__ h1, int M) {
  __shared__ u16 As[64][72];
  __shared__ u16 Bs[128][72];
  const int tid = threadIdx.x;
  const int lane = tid & 63, w = tid >> 6;
  const int row16 = lane & 15, quad = lane >> 4;
  const int rowBase = blockIdx.x * 64;
  f32x4 acc[8];
  #pragma unroll
  for (int nt = 0; nt < 8; ++nt) acc[nt] = (f32x4)(0.f);

  for (int kt = 0; kt < DIN; kt += 64) {
    {
      int r = tid >> 2, kq = tid & 3;
      int grow = rowBase + r;
      #pragma unroll
      for (int i = 0; i < 4; ++i) {
        float4 v = make_float4(0.f, 0.f, 0.f, 0.f);
        if (grow < M) v = *(const float4*)&x[(size_t)grow * DIN + kt + kq * 16 + i * 4];
        u32 lo = (u32)f2bf(v.x) | ((u32)f2bf(v.y) << 16);
        u32 hi = (u32)f2bf(v.z) | ((u32)f2bf(v.w) << 16);
        *(uint2*)&As[r][kq * 16 + i * 4] = make_uint2(lo, hi);
      }
    }
    {
      int n = tid >> 1, half = tid & 1;
      const uint4* s = (const uint4*)&w1t[n * DIN + kt + half * 32];
      uint4* d = (uint4*)&Bs[n][half * 32];
      d[0] = s[0]; d[1] = s[1]; d[2] = s[2]; d[3] = s[3];
    }
    __syncthreads();
    #pragma unroll
    for (int ks = 0; ks < 64; ks += 32) {
      bf16x8 a = *(bf16x8*)&As[w * 16 + row16][ks + quad * 8];
      #pragma unroll
      for (int nt = 0; nt < 8; ++nt) {
        bf16x8 b = *(bf16x8*)&Bs[nt * 16 + row16][ks + quad * 8];
        acc[nt] = __builtin_amdgcn_mfma_f32_16x16x32_bf16(a, b, acc[nt], 0, 0, 0);
      }
    }
    __syncthreads();
  }
  #pragma unroll
  for (int reg = 0; reg < 4; ++reg) {
    int row = rowBase + w * 16 + quad * 4 + reg;
    if (row < M) {
      float s = dinv[row];
      #pragma unroll
      for (int nt = 0; nt < 8; ++nt)
        h1[(size_t)row * DH + nt * 16 + row16] = f2bf(acc[nt][reg] * s);
    }
  }
}

// ---------- aggregate1 fused with layer-2 transform via MFMA ----------

__global__ __launch_bounds__(256) void aggregate1_fused(const u16* __restrict__ h,
    const int* __restrict__ rowptr, const u16* __restrict__ csr,
    const float* __restrict__ dinv, const float* __restrict__ bias,
    const u16* __restrict__ w2t, u16* __restrict__ h2, int n) {
  __shared__ __align__(16) u16 w2s[64 * 136];     // W2^T [64 cols][128 k], padded rows
  __shared__ __align__(16) u16 rowbuf[16 * 136];  // 16 M-rows (4 real), padded
  const int tid = threadIdx.x;
  const int lane = tid & 63;
  const int wv = tid >> 6;
  const int row16 = lane & 15, quad = lane >> 4;

  {   // stage W2^T: 64 rows x 16 uint4, row-padded
    #pragma unroll
    for (int i = 0; i < 4; ++i) {
      int flat = i * 256 + tid;                  // 0..1023
      int r = flat >> 4, q = flat & 15;
      *(uint4*)&w2s[r * 136 + q * 8] = *(const uint4*)&w2t[r * 128 + q * 8];
    }
  }
  if (wv < 3) {     // zero pad rows 4..15 of rowbuf (waves 0-2, one store/lane)
    int r = 4 + wv * 4 + quad;
    *(uint4*)&rowbuf[r * 136 + row16 * 8] = make_uint4(0, 0, 0, 0);
  }

  const int sub = quad;               // edge slot within quartet (0..3)
  const int l16 = row16;              // 16B chunk within 256B row
  const int nodeBase = blockIdx.x * 4;
  int node = nodeBase + wv;
  const bool active = node < n;
  node = __builtin_amdgcn_readfirstlane(active ? node : (n - 1));
  const float di = dinv[node];
  const size_t coff = (size_t)l16 * 8;

  float a[8];
  {   // self-loop row (only sub==0 keeps it)
    uint4 v = *(const uint4*)&h[(size_t)node * DH + coff];
    float ms = (sub == 0) ? 1.f : 0.f;
    a[0] = ms * bf2f_lo(v.x); a[1] = ms * bf2f_hi(v.x);
    a[2] = ms * bf2f_lo(v.y); a[3] = ms * bf2f_hi(v.y);
    a[4] = ms * bf2f_lo(v.z); a[5] = ms * bf2f_hi(v.z);
    a[6] = ms * bf2f_lo(v.w); a[7] = ms * bf2f_hi(v.w);
  }

  int p = rowptr[node];
  const int pe = active ? rowptr[node + 1] : p;   // inactive wave: empty range
  while (p < pe) {
    int g = p + lane;
    int si = (g < pe) ? (int)csr[g] : 0;     // 64 indices, one instruction
    int rem = pe - p; if (rem > 64) rem = 64;
    int t = 0;
    for (; t + 16 <= rem; t += 16) {         // 4 x 1KB gathers in flight
      #pragma unroll
      for (int q = 0; q < 4; ++q) {
        int idx = __shfl(si, t + q * 4 + sub, 64);
        uint4 v = *(const uint4*)&h[(size_t)idx * DH + coff];
        a[0] += bf2f_lo(v.x); a[1] += bf2f_hi(v.x);
        a[2] += bf2f_lo(v.y); a[3] += bf2f_hi(v.y);
        a[4] += bf2f_lo(v.z); a[5] += bf2f_hi(v.z);
        a[6] += bf2f_lo(v.w); a[7] += bf2f_hi(v.w);
      }
    }
    for (; t < rem; t += 4) {                // masked remainder (1-15 edges)
      int e = t + sub;
      int idx = __shfl(si, e & 63, 64);
      uint4 v = *(const uint4*)&h[(size_t)idx * DH + coff];
      float m = (e < rem) ? 1.f : 0.f;
      a[0] = fmaf(m, bf2f_lo(v.x), a[0]); a[1] = fmaf(m, bf2f_hi(v.x), a[1]);
      a[2] = fmaf(m, bf2f_lo(v.y), a[2]); a[3] = fmaf(m, bf2f_hi(v.y), a[3]);
      a[4] = fmaf(m, bf2f_lo(v.z), a[4]); a[5] = fmaf(m, bf2f_hi(v.z), a[5]);
      a[6] = fmaf(m, bf2f_lo(v.w), a[6]); a[7] = fmaf(m, bf2f_hi(v.w), a[7]);
    }
    p += 64;
  }

  #pragma unroll
  for (int i = 0; i < 8; ++i) {              // butterfly: every lane gets full sum
    a[i] += __shfl_xor(a[i], 16, 64);
    a[i] += __shfl_xor(a[i], 32, 64);
  }

  // g1 = relu(a*di + b1) -> bf16 -> rowbuf row wv (sub==0 lanes, one b128 store)
  if (sub == 0) {
    const int c0 = l16 * 8;
    float4 b0 = *(const float4*)&bias[c0];
    float4 b1v = *(const float4*)&bias[c0 + 4];
    float f0 = fmaxf(fmaf(a[0], di, b0.x), 0.f);
    float f1 = fmaxf(fmaf(a[1], di, b0.y), 0.f);
    float f2 = fmaxf(fmaf(a[2], di, b0.z), 0.f);
    float f3 = fmaxf(fmaf(a[3], di, b0.w), 0.f);
    float f4 = fmaxf(fmaf(a[4], di, b1v.x), 0.f);
    float f5 = fmaxf(fmaf(a[5], di, b1v.y), 0.f);
    float f6 = fmaxf(fmaf(a[6], di, b1v.z), 0.f);
    float f7 = fmaxf(fmaf(a[7], di, b1v.w), 0.f);
    uint4 pk;
    pk.x = (u32)f2bf(f0) | ((u32)f2bf(f1) << 16);
    pk.y = (u32)f2bf(f2) | ((u32)f2bf(f3) << 16);
    pk.z = (u32)f2bf(f4) | ((u32)f2bf(f5) << 16);
    pk.w = (u32)f2bf(f6) | ((u32)f2bf(f7) << 16);
    *(uint4*)&rowbuf[wv * 136 + l16 * 8] = pk;
  }
  __syncthreads();

  // block matmul: [16 x 128](rows 0-3 real) @ W2^T -> each wave owns 16 cols
  f32x4 acc = (f32x4)(0.f);
  #pragma unroll
  for (int kt = 0; kt < 4; ++kt) {
    bf16x8 af = *(bf16x8*)&rowbuf[row16 * 136 + kt * 32 + quad * 8];
    bf16x8 bf = *(bf16x8*)&w2s[(wv * 16 + row16) * 136 + kt * 32 + quad * 8];
    acc = __builtin_amdgcn_mfma_f32_16x16x32_bf16(af, bf, acc, 0, 0, 0);
  }
  // C layout: col = lane&15, row = (lane>>4)*4 + reg; rows 0-3 live in quad==0
  if (quad == 0) {
    #pragma unroll
    for (int reg = 0; reg < 4; ++reg) {
      int nr = nodeBase + reg;
      if (nr < n)
        h2[(size_t)nr * DOUT + wv * 16 + row16] = f2bf(acc[reg] * dinv[nr]);
    }
  }
}

// ---------- aggregate2: 8 edge-groups x 8 lanes, u16 csr ----------

__global__ __launch_bounds__(256) void aggregate2(const u16* __restrict__ h,
    const int* __restrict__ rowptr, const u16* __restrict__ csr,
    const float* __restrict__ dinv, const float* __restrict__ bias,
    float* __restrict__ out, int n) {
  const int lane = threadIdx.x & 63;
  const int sub = lane >> 3;          // edge slot within octet (0..7)
  const int l8 = lane & 7;            // 16B chunk within 128B row
  int node = blockIdx.x * 4 + (threadIdx.x >> 6);
  if (node >= n) return;
  node = __builtin_amdgcn_readfirstlane(node);
  const float di = dinv[node];
  const size_t coff = (size_t)l8 * 8;

  float a[8];
  {
    uint4 v = *(const uint4*)&h[(size_t)node * DOUT + coff];
    float ms = (sub == 0) ? 1.f : 0.f;
    a[0] = ms * bf2f_lo(v.x); a[1] = ms * bf2f_hi(v.x);
    a[2] = ms * bf2f_lo(v.y); a[3] = ms * bf2f_hi(v.y);
    a[4] = ms * bf2f_lo(v.z); a[5] = ms * bf2f_hi(v.z);
    a[6] = ms * bf2f_lo(v.w); a[7] = ms * bf2f_hi(v.w);
  }

  int p = rowptr[node];
  const int pe = rowptr[node + 1];
  while (p < pe) {
    int g = p + lane;
    int si = (g < pe) ? (int)csr[g] : 0;
    int rem = pe - p; if (rem > 64) rem = 64;
    int t = 0;
    for (; t + 32 <= rem; t += 32) {         // 4 x 1KB gathers in flight
      #pragma unroll
      for (int q = 0; q < 4; ++q) {
        int idx = __shfl(si, t + q * 8 + sub, 64);
        uint4 v = *(const uint4*)&h[(size_t)idx * DOUT + coff];
        a[0] += bf2f_lo(v.x); a[1] += bf2f_hi(v.x);
        a[2] += bf2f_lo(v.y); a[3] += bf2f_hi(v.y);
        a[4] += bf2f_lo(v.z); a[5] += bf2f_hi(v.z);
        a[6] += bf2f_lo(v.w); a[7] += bf2f_hi(v.w);
      }
    }
    for (; t < rem; t += 8) {                // masked remainder (1-31 edges)
      int e = t + sub;
      int idx = __shfl(si, e & 63, 64);
      uint4 v = *(const uint4*)&h[(size_t)idx * DOUT + coff];
      float m = (e < rem) ? 1.f : 0.f;
      a[0] = fmaf(m, bf2f_lo(v.x), a[0]); a[1] = fmaf(m, bf2f_hi(v.x), a[1]);
      a[2] = fmaf(m, bf2f_lo(v.y), a[2]); a[3] = fmaf(m, bf2f_hi(v.y), a[3]);
      a[4] = fmaf(m, bf2f_lo(v.z), a[4]); a[5] = fmaf(m, bf2f_hi(v.z), a[5]);
      a[6] = fmaf(m, bf2f_lo(v.w), a[6]); a[7] = fmaf(m, bf2f_hi(v.w), a[7]);
    }
    p += 64;
  }

  #pragma unroll
  for (int i = 0; i < 8; ++i) {              // reduce across the 8 edge-groups
    a[i] += __shfl_xor(a[i], 8, 64);
    a[i] += __shfl_xor(a[i], 16, 64);
    a[i] += __shfl_xor(a[i], 32, 64);
  }

  if (sub == 0) {                            // lanes 0..7 hold the full row
    const int c0 = l8 * 8;
    float4 b0 = *(const float4*)&bias[c0];
    float4 b1 = *(const float4*)&bias[c0 + 4];
    float4 r0, r1;
    r0.x = fmaf(a[0], di, b0.x);
    r0.y = fmaf(a[1], di, b0.y);
    r0.z = fmaf(a[2], di, b0.z);
    r0.w = fmaf(a[3], di, b0.w);
    r1.x = fmaf(a[4], di, b1.x);
    r1.y = fmaf(a[5], di, b1.y);
    r1.z = fmaf(a[6], di, b1.z);
    r1.w = fmaf(a[7], di, b1.w);
    *(float4*)&out[(size_t)node * DOUT + c0] = r0;
    *(float4*)&out[(size_t)node * DOUT + c0 + 4] = r1;
  }
}

// ---------- launch ----------

extern "C" void kernel_launch(void* const* d_in, const int* in_sizes, int n_in,
                              void* d_out, int out_size, void* d_ws, size_t ws_size,
                              hipStream_t stream) {
  const float* x  = (const float*)d_in[0];
  const int*   ei = (const int*)d_in[1];
  const float* W1 = (const float*)d_in[2];
  const float* b1 = (const float*)d_in[3];
  const float* W2 = (const float*)d_in[4];
  const float* b2 = (const float*)d_in[5];
  float* out = (float*)d_out;

  const int N = in_sizes[0] / DIN;   // 50000
  const int E = in_sizes[1] / 2;     // 1600000
  const int* src = ei;
  const int* dst = ei + E;
  const int nbuk = (N + BNODES - 1) / BNODES;   // 391 (<= MAXBUK)

  char* ws = (char*)d_ws;
  size_t o = 0;
  auto alloc = [&](size_t bytes) { size_t r = o; o += (bytes + 511) & ~(size_t)511; return r; };
  size_t bb_o      = alloc((size_t)(nbuk + 1) * 4);
  size_t counts_o  = alloc((size_t)nbuk * NBLK * 4);
  size_t rowptr_o  = alloc((size_t)(N + 1) * 4);
  size_t dinv_o    = alloc((size_t)N * 4);
  size_t w1t_o     = alloc((size_t)DH * DIN * 2);
  size_t w2t_o     = alloc((size_t)DOUT * DH * 2);
  size_t csr_o     = alloc((size_t)E * 2);        // u16 indices
  size_t h1_o      = alloc((size_t)N * DH * 2);   // bf16
  size_t big_o     = alloc((size_t)E * 4);        // ebuf, later h2
  size_t h2_o      = big_o;   // ebuf dead after bucket_finish -> h2 (bf16, 6.4MB)

  int*   bb      = (int*)(ws + bb_o);
  int*   counts  = (int*)(ws + counts_o);
  int*   rowptr  = (int*)(ws + rowptr_o);
  float* dinv    = (float*)(ws + dinv_o);
  u16*   w1t     = (u16*)(ws + w1t_o);
  u16*   w2t     = (u16*)(ws + w2t_o);
  u16*   csr     = (u16*)(ws + csr_o);
  u16*   h1      = (u16*)(ws + h1_o);
  u32*   ebuf    = (u32*)(ws + big_o);
  u16*   h2      = (u16*)(ws + h2_o);

  w_prep<<<(DH * DIN + DOUT * DH) / 256, 256, 0, stream>>>(W1, W2, w1t, w2t);
  hist_kernel<<<NBLK, 256, 0, stream>>>(dst, counts, E, nbuk);
  col_scan<<<nbuk, 256, 0, stream>>>(counts, bb, nbuk);
  scan_block<<<1, 256, 0, stream>>>(bb, bb, nbuk, nbuk);          // bb -> exclusive, bb[nbuk]=E
  scatter_kernel<<<NBLK, 256, 0, stream>>>(src, dst, counts, bb, ebuf, E, nbuk);
  bucket_finish<<<nbuk, 256, 0, stream>>>(ebuf, bb, rowptr, dinv, csr, N, nbuk);

  gemm1_mfma<<<(N + 63) / 64, 256, 0, stream>>>(x, w1t, dinv, h1, N);
  aggregate1_fused<<<(N + 3) / 4, 256, 0, stream>>>(h1, rowptr, csr, dinv, b1, w2t, h2, N);
  aggregate2<<<(N + 3) / 4, 256, 0, stream>>>(h2, rowptr, csr, dinv, b2, out, N);
}